// Round 1
// baseline (903.964 us; speedup 1.0000x reference)
//
#include <hip/hip_runtime.h>
#include <math.h>

#define BSZ  16
#define DIM  768
#define SEQA 1024
#define SEQB 1024

// ---- float <-> order-preserving uint key (for atomicMax on floats incl. -inf) ----
__device__ inline unsigned enc_key(float f) {
    unsigned u = __float_as_uint(f);
    return (u & 0x80000000u) ? ~u : (u | 0x80000000u);
}
__device__ inline float dec_key(unsigned k) {
    return (k & 0x80000000u) ? __uint_as_float(k ^ 0x80000000u) : __uint_as_float(~k);
}

// ---- init: rowmax/colmax keys to 0 (== -NaN/-inf floor; every slot gets >=1 update) ----
__global__ void k0_init(unsigned* __restrict__ keyA, unsigned* __restrict__ keyB) {
    int i = blockIdx.x * 256 + threadIdx.x;
    if (i < BSZ * SEQA) keyA[i] = 0u;
    if (i < BSZ * SEQB) keyB[i] = 0u;
}

// ---- k1: C[b,e,s] = sum_d U[d,e] * A[b,d,s]   (per-batch U^T @ A) ----
// grid (SEQA/64, DIM/64, BSZ), block 256, 4x4 microtile per thread
__global__ __launch_bounds__(256) void k1_ua(const float* __restrict__ U,
                                             const float* __restrict__ A,
                                             float* __restrict__ C) {
    __shared__ float Us[16][64];  // [k][e]
    __shared__ float As[16][64];  // [k][s]
    const int b  = blockIdx.z;
    const int e0 = blockIdx.y * 64;
    const int s0 = blockIdx.x * 64;
    const int tid = threadIdx.x;
    const int ee = tid & 63, kq = tid >> 6;   // loader coords
    const int c  = tid & 15, r  = tid >> 4;   // compute coords
    const float* Ab = A + (size_t)b * DIM * SEQA;
    float acc[4][4] = {};
    for (int k0 = 0; k0 < DIM; k0 += 16) {
#pragma unroll
        for (int i = 0; i < 4; i++) {
            int kk = kq + 4 * i;
            Us[kk][ee] = U[(size_t)(k0 + kk) * DIM + (e0 + ee)];
            As[kk][ee] = Ab[(size_t)(k0 + kk) * SEQA + (s0 + ee)];
        }
        __syncthreads();
#pragma unroll
        for (int kk = 0; kk < 16; kk++) {
            float ur[4], ar[4];
#pragma unroll
            for (int i = 0; i < 4; i++) ur[i] = Us[kk][r + 16 * i];
#pragma unroll
            for (int j = 0; j < 4; j++) ar[j] = As[kk][c + 16 * j];
#pragma unroll
            for (int i = 0; i < 4; i++)
#pragma unroll
                for (int j = 0; j < 4; j++) acc[i][j] += ur[i] * ar[j];
        }
        __syncthreads();
    }
    float* Cb = C + (size_t)b * DIM * SEQA;
#pragma unroll
    for (int i = 0; i < 4; i++)
#pragma unroll
        for (int j = 0; j < 4; j++)
            Cb[(size_t)(e0 + r + 16 * i) * SEQA + (s0 + c + 16 * j)] = acc[i][j];
}

// ---- k2: align tile = tanh(C[b,:,s]^T B[b,:,t]) + msk; fused row/col max reduction ----
// grid (SEQB/64, SEQA/64, BSZ), block 256
__global__ __launch_bounds__(256) void k2_align(const float* __restrict__ C,
                                                const float* __restrict__ B,
                                                const float* __restrict__ msk,
                                                unsigned* __restrict__ keyA,
                                                unsigned* __restrict__ keyB) {
    __shared__ float Cs[16][64];
    __shared__ float Bs[16][64];
    __shared__ float red[64][17];
    const int b  = blockIdx.z;
    const int s0 = blockIdx.y * 64;
    const int t0 = blockIdx.x * 64;
    const int tid = threadIdx.x;
    const int ee = tid & 63, kq = tid >> 6;
    const int c  = tid & 15, r  = tid >> 4;
    const float* Cb = C + (size_t)b * DIM * SEQA;
    const float* Bb = B + (size_t)b * DIM * SEQB;
    float acc[4][4] = {};
    for (int k0 = 0; k0 < DIM; k0 += 16) {
#pragma unroll
        for (int i = 0; i < 4; i++) {
            int kk = kq + 4 * i;
            Cs[kk][ee] = Cb[(size_t)(k0 + kk) * SEQA + (s0 + ee)];
            Bs[kk][ee] = Bb[(size_t)(k0 + kk) * SEQB + (t0 + ee)];
        }
        __syncthreads();
#pragma unroll
        for (int kk = 0; kk < 16; kk++) {
            float cr[4], br[4];
#pragma unroll
            for (int i = 0; i < 4; i++) cr[i] = Cs[kk][r + 16 * i];
#pragma unroll
            for (int j = 0; j < 4; j++) br[j] = Bs[kk][c + 16 * j];
#pragma unroll
            for (int i = 0; i < 4; i++)
#pragma unroll
                for (int j = 0; j < 4; j++) acc[i][j] += cr[i] * br[j];
        }
        __syncthreads();
    }
    // tanh + mask
    const float* Mb = msk + (size_t)b * SEQA * SEQB;
    float val[4][4];
#pragma unroll
    for (int i = 0; i < 4; i++) {
        const float* Mrow = Mb + (size_t)(s0 + r + 16 * i) * SEQB + t0;
#pragma unroll
        for (int j = 0; j < 4; j++)
            val[i][j] = tanhf(acc[i][j]) + Mrow[c + 16 * j];
    }
    // row maxes (over t within tile) -> keyA[b,s]
#pragma unroll
    for (int i = 0; i < 4; i++) {
        float m = fmaxf(fmaxf(val[i][0], val[i][1]), fmaxf(val[i][2], val[i][3]));
        red[r + 16 * i][c] = m;
    }
    __syncthreads();
    if (tid < 64) {
        float m = red[tid][0];
#pragma unroll
        for (int cc = 1; cc < 16; cc++) m = fmaxf(m, red[tid][cc]);
        atomicMax(&keyA[b * SEQA + s0 + tid], enc_key(m));
    }
    __syncthreads();
    // col maxes (over s within tile) -> keyB[b,t]
#pragma unroll
    for (int j = 0; j < 4; j++) {
        float m = fmaxf(fmaxf(val[0][j], val[1][j]), fmaxf(val[2][j], val[3][j]));
        red[c + 16 * j][r] = m;
    }
    __syncthreads();
    if (tid < 64) {
        float m = red[tid][0];
#pragma unroll
        for (int rr = 1; rr < 16; rr++) m = fmaxf(m, red[tid][rr]);
        atomicMax(&keyB[b * SEQB + t0 + tid], enc_key(m));
    }
}

// ---- k3: softmax over the per-token maxes ----
// grid (BSZ, 2), block 256; each thread owns 4 elements of the 1024-vector
__global__ __launch_bounds__(256) void k3_softmax(const unsigned* __restrict__ keyA,
                                                  const unsigned* __restrict__ keyB,
                                                  float* __restrict__ scoreA,
                                                  float* __restrict__ scoreB) {
    const int b = blockIdx.x;
    const bool isA = (blockIdx.y == 0);
    const unsigned* keys = isA ? (keyA + b * SEQA) : (keyB + b * SEQB);
    float* score = isA ? (scoreA + b * SEQA) : (scoreB + b * SEQB);
    __shared__ float sh[4];
    const int tid = threadIdx.x;
    float m[4];
    float mx = -INFINITY;
#pragma unroll
    for (int k = 0; k < 4; k++) {
        m[k] = dec_key(keys[tid + 256 * k]);
        mx = fmaxf(mx, m[k]);
    }
#pragma unroll
    for (int o = 32; o > 0; o >>= 1) mx = fmaxf(mx, __shfl_down(mx, o, 64));
    if ((tid & 63) == 0) sh[tid >> 6] = mx;
    __syncthreads();
    mx = fmaxf(fmaxf(sh[0], sh[1]), fmaxf(sh[2], sh[3]));
    __syncthreads();
    float e[4];
    float sum = 0.f;
#pragma unroll
    for (int k = 0; k < 4; k++) { e[k] = expf(m[k] - mx); sum += e[k]; }
#pragma unroll
    for (int o = 32; o > 0; o >>= 1) sum += __shfl_down(sum, o, 64);
    if ((tid & 63) == 0) sh[tid >> 6] = sum;
    __syncthreads();
    sum = sh[0] + sh[1] + sh[2] + sh[3];
    float inv = 1.0f / sum;
#pragma unroll
    for (int k = 0; k < 4; k++) score[tid + 256 * k] = e[k] * inv;
}

// ---- k4: out[b,d] = sum_s X[b,d,s] * score[b,s]  (one wave per row, float4 loads) ----
// grid (BSZ*DIM/4, 2), block 256 (4 waves)
__global__ __launch_bounds__(256) void k4_out(const float* __restrict__ A,
                                              const float* __restrict__ B,
                                              const float* __restrict__ scoreA,
                                              const float* __restrict__ scoreB,
                                              float* __restrict__ out) {
    const int which = blockIdx.y;
    const int row = blockIdx.x * 4 + (threadIdx.x >> 6);  // row = b*DIM + d
    const int lane = threadIdx.x & 63;
    const float* X = which ? B : A;
    const float* S = which ? scoreB : scoreA;
    const int b = row / DIM;
    const float4* xr = (const float4*)(X + (size_t)row * SEQA);
    const float4* sr = (const float4*)(S + (size_t)b * SEQA);
    float acc = 0.f;
#pragma unroll
    for (int q = lane; q < SEQA / 4; q += 64) {
        float4 x = xr[q];
        float4 s = sr[q];
        acc += x.x * s.x + x.y * s.y + x.z * s.z + x.w * s.w;
    }
#pragma unroll
    for (int o = 32; o > 0; o >>= 1) acc += __shfl_down(acc, o, 64);
    if (lane == 0) out[which * (BSZ * DIM) + row] = acc;
}

extern "C" void kernel_launch(void* const* d_in, const int* in_sizes, int n_in,
                              void* d_out, int out_size, void* d_ws, size_t ws_size,
                              hipStream_t stream) {
    const float* A   = (const float*)d_in[0];  // (16,768,1024)
    const float* B   = (const float*)d_in[1];  // (16,768,1024)
    const float* msk = (const float*)d_in[2];  // (16,1024,1024)
    const float* U   = (const float*)d_in[3];  // (768,768)
    float* out = (float*)d_out;                // [output_A | output_B] = 2*16*768

    // workspace layout
    char* ws = (char*)d_ws;
    float*    C      = (float*)ws;                       // 16*768*1024 f32 = 50,331,648 B
    size_t off = (size_t)BSZ * DIM * SEQA * sizeof(float);
    unsigned* keyA   = (unsigned*)(ws + off); off += (size_t)BSZ * SEQA * sizeof(unsigned);
    unsigned* keyB   = (unsigned*)(ws + off); off += (size_t)BSZ * SEQB * sizeof(unsigned);
    float*    scoreA = (float*)(ws + off);    off += (size_t)BSZ * SEQA * sizeof(float);
    float*    scoreB = (float*)(ws + off);

    k0_init<<<(BSZ * SEQA + 255) / 256, 256, 0, stream>>>(keyA, keyB);
    {
        dim3 g(SEQA / 64, DIM / 64, BSZ);
        k1_ua<<<g, 256, 0, stream>>>(U, A, C);
    }
    {
        dim3 g(SEQB / 64, SEQA / 64, BSZ);
        k2_align<<<g, 256, 0, stream>>>(C, B, msk, keyA, keyB);
    }
    {
        dim3 g(BSZ, 2);
        k3_softmax<<<g, 256, 0, stream>>>(keyA, keyB, scoreA, scoreB);
    }
    {
        dim3 g(BSZ * DIM / 4, 2);
        k4_out<<<g, 256, 0, stream>>>(A, B, scoreA, scoreB, out);
    }
}

// Round 2
// 324.372 us; speedup vs baseline: 2.7868x; 2.7868x over previous
//
#include <hip/hip_runtime.h>
#include <math.h>

#define BSZ  16
#define DIM  768
#define SEQA 1024
#define SEQB 1024

typedef __bf16 bf16x8 __attribute__((ext_vector_type(8)));
typedef float  f32x4  __attribute__((ext_vector_type(4)));

__device__ inline unsigned short f2bf(float f) {
    __bf16 h = (__bf16)f;
    return __builtin_bit_cast(unsigned short, h);
}

__device__ inline void gload_lds16(const void* g, void* l) {
    __builtin_amdgcn_global_load_lds(
        (const __attribute__((address_space(1))) void*)g,
        (__attribute__((address_space(3))) void*)l, 16, 0, 0);
}

// ---- float <-> order-preserving uint key (for atomicMax on floats) ----
__device__ inline unsigned enc_key(float f) {
    unsigned u = __float_as_uint(f);
    return (u & 0x80000000u) ? ~u : (u | 0x80000000u);
}
__device__ inline float dec_key(unsigned k) {
    return (k & 0x80000000u) ? __uint_as_float(k ^ 0x80000000u) : __uint_as_float(~k);
}

__global__ void k0_init(unsigned* __restrict__ keyA, unsigned* __restrict__ keyB) {
    int i = blockIdx.x * 256 + threadIdx.x;
    if (i < BSZ * SEQA) keyA[i] = 0u;
    if (i < BSZ * SEQB) keyB[i] = 0u;
}

// ---- pre-pass: B[b][e][t] f32 -> Bt[b][t][e] bf16 ----
__global__ __launch_bounds__(256) void t_cast_B(const float* __restrict__ B,
                                                unsigned short* __restrict__ Bt) {
    __shared__ float tl[64][65];
    const int b = blockIdx.z;
    const int e0 = blockIdx.y * 64;
    const int t0 = blockIdx.x * 64;
    const int tid = threadIdx.x;
    const int c = tid & 63, r4 = tid >> 6;
    const float* Bb = B + ((size_t)b * DIM + e0) * SEQB + t0;
#pragma unroll
    for (int i = 0; i < 64; i += 4)
        tl[i + r4][c] = Bb[(size_t)(i + r4) * SEQB + c];
    __syncthreads();
    unsigned short* Bo = Bt + ((size_t)b * SEQB + t0) * DIM + e0;
#pragma unroll
    for (int i = 0; i < 64; i += 4)
        Bo[(size_t)(i + r4) * DIM + c] = f2bf(tl[c][i + r4]);
}

// ---- pre-pass: U[d][e] f32 -> Ut[e][d] bf16 ----
__global__ __launch_bounds__(256) void t_cast_U(const float* __restrict__ U,
                                                unsigned short* __restrict__ Ut) {
    __shared__ float tl[64][65];
    const int d0 = blockIdx.y * 64;
    const int e0 = blockIdx.x * 64;
    const int tid = threadIdx.x;
    const int c = tid & 63, r4 = tid >> 6;
#pragma unroll
    for (int i = 0; i < 64; i += 4)
        tl[i + r4][c] = U[(size_t)(d0 + i + r4) * DIM + e0 + c];
    __syncthreads();
#pragma unroll
    for (int i = 0; i < 64; i += 4)
        Ut[(size_t)(e0 + i + r4) * DIM + d0 + c] = f2bf(tl[c][i + r4]);
}

// ---- k1: Ct[b][s][e] = sum_d A[b][d][s] * U[d][e]   (bf16 MFMA, 128x128 tile) ----
// grid (SEQA/128, DIM/128, BSZ), block 256 (4 waves, each 64x64)
__global__ __launch_bounds__(256) void k1_ua(const float* __restrict__ A,
                                             const unsigned short* __restrict__ Ut,
                                             unsigned short* __restrict__ Ct) {
    __shared__ __align__(16) unsigned short As_t[128 * 40]; // [s][d], pad 32->40 (2-way free)
    __shared__ __align__(16) unsigned short Us_t[128 * 32]; // [e][d], global_load_lds layout
    const int b  = blockIdx.z;
    const int s0 = blockIdx.x * 128;
    const int e0 = blockIdx.y * 128;
    const int tid  = threadIdx.x;
    const int lane = tid & 63;
    const int wid  = tid >> 6;
    const int wr = wid >> 1, wc = wid & 1;
    const int quad = lane >> 4, l15 = lane & 15;
    const int sq  = tid & 31;   // A-stage: s quad (coalesced global reads)
    const int dp0 = tid >> 5;   // A-stage: d pair

    const float* Ab = A + (size_t)b * DIM * SEQA;
    f32x4 acc[4][4] = {};

    for (int d0 = 0; d0 < DIM; d0 += 32) {
        // U tile via global_load_lds (Ut rows: 32 bf16 = 64 B)
#pragma unroll
        for (int t = 0; t < 2; ++t) {
            int p = wid * 2 + t;
            const unsigned short* g =
                Ut + (size_t)(e0 + p * 16 + (lane >> 2)) * DIM + d0 + (lane & 3) * 8;
            gload_lds16(g, Us_t + p * 512);
        }
        // A tile: transpose-stage f32 -> bf16 pairs, 2-way-conflict-free writes
#pragma unroll
        for (int it = 0; it < 2; ++it) {
            int dp = dp0 + it * 8;
            const float* g = Ab + (size_t)(d0 + 2 * dp) * SEQA + s0 + 4 * sq;
            float4 x = *(const float4*)g;
            float4 y = *(const float4*)(g + SEQA);
            const float* xp = (const float*)&x;
            const float* yp = (const float*)&y;
#pragma unroll
            for (int q = 0; q < 4; ++q) {
                unsigned v = (unsigned)f2bf(xp[q]) | ((unsigned)f2bf(yp[q]) << 16);
                *(unsigned*)&As_t[(4 * sq + q) * 40 + 2 * dp] = v;
            }
        }
        __syncthreads();
        bf16x8 av[4], bv[4];
#pragma unroll
        for (int i = 0; i < 4; ++i)
            av[i] = *(const bf16x8*)&As_t[(wr * 64 + 16 * i + l15) * 40 + quad * 8];
#pragma unroll
        for (int j = 0; j < 4; ++j)
            bv[j] = *(const bf16x8*)&Us_t[(wc * 64 + 16 * j + l15) * 32 + quad * 8];
#pragma unroll
        for (int i = 0; i < 4; ++i)
#pragma unroll
            for (int j = 0; j < 4; ++j)
                acc[i][j] = __builtin_amdgcn_mfma_f32_16x16x32_bf16(av[i], bv[j], acc[i][j], 0, 0, 0);
        __syncthreads();
    }
    // store Ct (D layout: col = l15, row = quad*4+reg)
#pragma unroll
    for (int i = 0; i < 4; ++i)
#pragma unroll
        for (int j = 0; j < 4; ++j) {
            int e_g = e0 + wc * 64 + 16 * j + l15;
#pragma unroll
            for (int r = 0; r < 4; ++r) {
                int s_g = s0 + wr * 64 + 16 * i + quad * 4 + r;
                Ct[(size_t)(b * SEQA + s_g) * DIM + e_g] = f2bf(acc[i][j][r]);
            }
        }
}

// ---- k2: tile = tanh(Ct^T Bt) + msk; fused row/col max -> atomic keys ----
// grid (SEQB/128, SEQA/128, BSZ), block 256
__global__ __launch_bounds__(256) void k2_align(const unsigned short* __restrict__ Ct,
                                                const unsigned short* __restrict__ Bt,
                                                const float* __restrict__ msk,
                                                unsigned* __restrict__ keyA,
                                                unsigned* __restrict__ keyB) {
    __shared__ __align__(16) unsigned short Cs[128 * 32];
    __shared__ __align__(16) unsigned short Bs[128 * 32];
    const int b  = blockIdx.z;
    const int t0 = blockIdx.x * 128;
    const int s0 = blockIdx.y * 128;
    const int tid  = threadIdx.x;
    const int lane = tid & 63;
    const int wid  = tid >> 6;
    const int wr = wid >> 1, wc = wid & 1;
    const int quad = lane >> 4, l15 = lane & 15;

    f32x4 acc[4][4] = {};

    for (int e0 = 0; e0 < DIM; e0 += 32) {
#pragma unroll
        for (int t = 0; t < 2; ++t) {
            int p = wid * 2 + t;
            gload_lds16(Ct + (size_t)(b * SEQA + s0 + p * 16 + (lane >> 2)) * DIM + e0 + (lane & 3) * 8,
                        Cs + p * 512);
            gload_lds16(Bt + (size_t)(b * SEQB + t0 + p * 16 + (lane >> 2)) * DIM + e0 + (lane & 3) * 8,
                        Bs + p * 512);
        }
        __syncthreads();
        bf16x8 av[4], bv[4];
#pragma unroll
        for (int i = 0; i < 4; ++i)
            av[i] = *(const bf16x8*)&Cs[(wr * 64 + 16 * i + l15) * 32 + quad * 8];
#pragma unroll
        for (int j = 0; j < 4; ++j)
            bv[j] = *(const bf16x8*)&Bs[(wc * 64 + 16 * j + l15) * 32 + quad * 8];
#pragma unroll
        for (int i = 0; i < 4; ++i)
#pragma unroll
            for (int j = 0; j < 4; ++j)
                acc[i][j] = __builtin_amdgcn_mfma_f32_16x16x32_bf16(av[i], bv[j], acc[i][j], 0, 0, 0);
        __syncthreads();
    }

    // epilogue: tanh + mask (in place)
    const float* Mb = msk + (size_t)b * SEQA * SEQB;
#pragma unroll
    for (int i = 0; i < 4; ++i)
#pragma unroll
        for (int j = 0; j < 4; ++j) {
            int t_g = t0 + wc * 64 + 16 * j + l15;
#pragma unroll
            for (int r = 0; r < 4; ++r) {
                int s_g = s0 + wr * 64 + 16 * i + quad * 4 + r;
                acc[i][j][r] = tanhf(acc[i][j][r]) + Mb[(size_t)s_g * SEQB + t_g];
            }
        }
    // row maxes: max over j + lanes sharing quad (cols), then atomic per row
#pragma unroll
    for (int i = 0; i < 4; ++i)
#pragma unroll
        for (int r = 0; r < 4; ++r) {
            float m = fmaxf(fmaxf(acc[i][0][r], acc[i][1][r]), fmaxf(acc[i][2][r], acc[i][3][r]));
            m = fmaxf(m, __shfl_xor(m, 1));
            m = fmaxf(m, __shfl_xor(m, 2));
            m = fmaxf(m, __shfl_xor(m, 4));
            m = fmaxf(m, __shfl_xor(m, 8));
            if (l15 == 0)
                atomicMax(&keyA[b * SEQA + s0 + wr * 64 + 16 * i + quad * 4 + r], enc_key(m));
        }
    // col maxes: max over i,reg in-lane, then across quads
#pragma unroll
    for (int j = 0; j < 4; ++j) {
        float m = -INFINITY;
#pragma unroll
        for (int i = 0; i < 4; ++i)
#pragma unroll
            for (int r = 0; r < 4; ++r) m = fmaxf(m, acc[i][j][r]);
        m = fmaxf(m, __shfl_xor(m, 16));
        m = fmaxf(m, __shfl_xor(m, 32));
        if (quad == 0)
            atomicMax(&keyB[b * SEQB + t0 + wc * 64 + 16 * j + l15], enc_key(m));
    }
}

// ---- k3: softmax over per-token maxes ----
__global__ __launch_bounds__(256) void k3_softmax(const unsigned* __restrict__ keyA,
                                                  const unsigned* __restrict__ keyB,
                                                  float* __restrict__ scoreA,
                                                  float* __restrict__ scoreB) {
    const int b = blockIdx.x;
    const bool isA = (blockIdx.y == 0);
    const unsigned* keys = isA ? (keyA + b * SEQA) : (keyB + b * SEQB);
    float* score = isA ? (scoreA + b * SEQA) : (scoreB + b * SEQB);
    __shared__ float sh[4];
    const int tid = threadIdx.x;
    float m[4];
    float mx = -INFINITY;
#pragma unroll
    for (int k = 0; k < 4; k++) {
        m[k] = dec_key(keys[tid + 256 * k]);
        mx = fmaxf(mx, m[k]);
    }
#pragma unroll
    for (int o = 32; o > 0; o >>= 1) mx = fmaxf(mx, __shfl_down(mx, o, 64));
    if ((tid & 63) == 0) sh[tid >> 6] = mx;
    __syncthreads();
    mx = fmaxf(fmaxf(sh[0], sh[1]), fmaxf(sh[2], sh[3]));
    __syncthreads();
    float e[4];
    float sum = 0.f;
#pragma unroll
    for (int k = 0; k < 4; k++) { e[k] = expf(m[k] - mx); sum += e[k]; }
#pragma unroll
    for (int o = 32; o > 0; o >>= 1) sum += __shfl_down(sum, o, 64);
    if ((tid & 63) == 0) sh[tid >> 6] = sum;
    __syncthreads();
    sum = sh[0] + sh[1] + sh[2] + sh[3];
    float inv = 1.0f / sum;
#pragma unroll
    for (int k = 0; k < 4; k++) score[tid + 256 * k] = e[k] * inv;
}

// ---- k4: out[b,d] = sum_s X[b,d,s] * score[b,s] ----
__global__ __launch_bounds__(256) void k4_out(const float* __restrict__ A,
                                              const float* __restrict__ B,
                                              const float* __restrict__ scoreA,
                                              const float* __restrict__ scoreB,
                                              float* __restrict__ out) {
    const int which = blockIdx.y;
    const int row = blockIdx.x * 4 + (threadIdx.x >> 6);
    const int lane = threadIdx.x & 63;
    const float* X = which ? B : A;
    const float* S = which ? scoreB : scoreA;
    const int b = row / DIM;
    const float4* xr = (const float4*)(X + (size_t)row * SEQA);
    const float4* sr = (const float4*)(S + (size_t)b * SEQA);
    float acc = 0.f;
#pragma unroll
    for (int q = lane; q < SEQA / 4; q += 64) {
        float4 x = xr[q];
        float4 s = sr[q];
        acc += x.x * s.x + x.y * s.y + x.z * s.z + x.w * s.w;
    }
#pragma unroll
    for (int o = 32; o > 0; o >>= 1) acc += __shfl_down(acc, o, 64);
    if (lane == 0) out[which * (BSZ * DIM) + row] = acc;
}

extern "C" void kernel_launch(void* const* d_in, const int* in_sizes, int n_in,
                              void* d_out, int out_size, void* d_ws, size_t ws_size,
                              hipStream_t stream) {
    const float* A   = (const float*)d_in[0];  // (16,768,1024)
    const float* B   = (const float*)d_in[1];  // (16,768,1024)
    const float* msk = (const float*)d_in[2];  // (16,1024,1024)
    const float* U   = (const float*)d_in[3];  // (768,768)
    float* out = (float*)d_out;

    // workspace layout (all 16B-aligned offsets)
    char* ws = (char*)d_ws;
    unsigned short* Ct = (unsigned short*)ws;                       // 25,165,824 B
    unsigned short* Bt = (unsigned short*)(ws + 25165824);          // 25,165,824 B
    unsigned short* Ut = (unsigned short*)(ws + 50331648);          //  1,179,648 B
    unsigned* keyA   = (unsigned*)(ws + 51511296);
    unsigned* keyB   = (unsigned*)(ws + 51576832);
    float*    scoreA = (float*)   (ws + 51642368);
    float*    scoreB = (float*)   (ws + 51707904);

    k0_init<<<64, 256, 0, stream>>>(keyA, keyB);
    t_cast_U<<<dim3(DIM / 64, DIM / 64, 1), 256, 0, stream>>>(U, Ut);
    t_cast_B<<<dim3(SEQB / 64, DIM / 64, BSZ), 256, 0, stream>>>(B, Bt);
    k1_ua<<<dim3(SEQA / 128, DIM / 128, BSZ), 256, 0, stream>>>(A, Ut, Ct);
    k2_align<<<dim3(SEQB / 128, SEQA / 128, BSZ), 256, 0, stream>>>(Ct, Bt, msk, keyA, keyB);
    k3_softmax<<<dim3(BSZ, 2), 256, 0, stream>>>(keyA, keyB, scoreA, scoreB);
    k4_out<<<dim3(BSZ * DIM / 4, 2), 256, 0, stream>>>(A, B, scoreA, scoreB, out);
}

// Round 3
// 259.844 us; speedup vs baseline: 3.4789x; 1.2483x over previous
//
#include <hip/hip_runtime.h>
#include <math.h>

#define BSZ  16
#define DIM  768
#define SEQA 1024
#define SEQB 1024

typedef float f32x4 __attribute__((ext_vector_type(4)));
typedef long long llong;

__device__ inline void gload_lds16(const void* g, void* l) {
    __builtin_amdgcn_global_load_lds(
        (const __attribute__((address_space(1))) void*)g,
        (__attribute__((address_space(3))) void*)l, 16, 0, 0);
}

// ---- float <-> order-preserving uint key (atomicMax on floats) ----
__device__ inline unsigned enc_key(float f) {
    unsigned u = __float_as_uint(f);
    return (u & 0x80000000u) ? ~u : (u | 0x80000000u);
}
__device__ inline float dec_key(unsigned k) {
    return (k & 0x80000000u) ? __uint_as_float(k ^ 0x80000000u) : __uint_as_float(~k);
}

// ---- fp8 e4m3 (OCP on gfx950) pack helpers ----
__device__ inline unsigned pk4_fp8(float a, float b, float c, float d) {
    int v = 0;
    v = __builtin_amdgcn_cvt_pk_fp8_f32(a, b, v, false);
    v = __builtin_amdgcn_cvt_pk_fp8_f32(c, d, v, true);
    return (unsigned)v;
}
__device__ inline unsigned char f2fp8(float a) {
    return (unsigned char)(__builtin_amdgcn_cvt_pk_fp8_f32(a, a, 0, false) & 0xFF);
}

// tanh via hardware exp: exact 1.0f in saturation, ~1e-6 error mid-range
__device__ inline float fast_tanh(float x) {
    float ax = fabsf(x);
    float u = __expf(-2.0f * ax);
    float th = __fdividef(1.0f - u, 1.0f + u);
    return copysignf(th, x);
}

// ---- prepass: X[b][DIM][SEQ] f32 -> Xt[b][SEQ][DIM] fp8 for A (z<16) and B (z>=16) ----
__global__ __launch_bounds__(256) void t_cast_AB(const float* __restrict__ A,
                                                 const float* __restrict__ B,
                                                 unsigned char* __restrict__ At,
                                                 unsigned char* __restrict__ Bt) {
    __shared__ float tl[64][65];
    const int z = blockIdx.z;
    const float* X = (z < BSZ) ? A : B;
    unsigned char* Y = (z < BSZ) ? At : Bt;
    const int b = z & 15;
    const int d0 = blockIdx.y * 64;
    const int s0 = blockIdx.x * 64;
    const int tid = threadIdx.x;
    const int c = tid & 63, r4 = tid >> 6;
    const float* Xb = X + ((size_t)b * DIM + d0) * SEQA + s0;
#pragma unroll
    for (int i = 0; i < 64; i += 4)
        tl[i + r4][c] = Xb[(size_t)(i + r4) * SEQA + c];
    __syncthreads();
    unsigned char* Yb = Y + ((size_t)b * SEQA + s0) * DIM + d0;
    const int m = tid & 15, sl = tid >> 4;
#pragma unroll
    for (int i = 0; i < 4; i++) {
        int s = sl + 16 * i;
        unsigned v = pk4_fp8(tl[4 * m + 0][s], tl[4 * m + 1][s], tl[4 * m + 2][s], tl[4 * m + 3][s]);
        *(unsigned*)&Yb[(size_t)s * DIM + 4 * m] = v;
    }
}

// ---- prepass: U[d][e] f32 -> Ut[e][d] fp8 ; also init max-keys ----
__global__ __launch_bounds__(256) void t_cast_U(const float* __restrict__ U,
                                                unsigned char* __restrict__ Ut,
                                                unsigned* __restrict__ keyA,
                                                unsigned* __restrict__ keyB) {
    __shared__ float tl[64][65];
    const int d0 = blockIdx.y * 64;
    const int e0 = blockIdx.x * 64;
    const int tid = threadIdx.x;
    const int bid = blockIdx.y * gridDim.x + blockIdx.x;
    if (bid < 64) {
        int i = bid * 256 + tid;
        keyA[i] = 0u;
        keyB[i] = 0u;
    }
    const int c = tid & 63, r4 = tid >> 6;
#pragma unroll
    for (int i = 0; i < 64; i += 4)
        tl[i + r4][c] = U[(size_t)(d0 + i + r4) * DIM + e0 + c];
    __syncthreads();
    const int m = tid & 15, sl = tid >> 4;
#pragma unroll
    for (int i = 0; i < 4; i++) {
        int e = sl + 16 * i;
        unsigned v = pk4_fp8(tl[4 * m + 0][e], tl[4 * m + 1][e], tl[4 * m + 2][e], tl[4 * m + 3][e]);
        *(unsigned*)&Ut[(size_t)(e0 + e) * DIM + d0 + 4 * m] = v;
    }
}

// ---- k1: Ct[b][s][e] = sum_d At[b][s][d] * Ut[e][d]  (fp8 MFMA, 128x128 tile, BK=64) ----
__global__ __launch_bounds__(256) void k1_ua(const unsigned char* __restrict__ At,
                                             const unsigned char* __restrict__ Ut,
                                             unsigned char* __restrict__ Ct) {
    __shared__ __align__(16) unsigned char As[2][4096];
    __shared__ __align__(16) unsigned char Us[2][4096];
    const int b  = blockIdx.z;
    const int s0 = blockIdx.x * 128;
    const int e0 = blockIdx.y * 128;
    const int tid = threadIdx.x;
    const int lane = tid & 63;
    const int wid = tid >> 6;
    const int wr = wid >> 1, wc = wid & 1;
    const int quad = lane >> 4, l15 = lane & 15;
    const int grow = lane >> 1, gcol = (lane & 1) * 16;

    const unsigned char* Atb = At + (size_t)b * SEQA * DIM;
    f32x4 acc[4][4] = {};

    for (int d0 = 0; d0 < DIM; d0 += 64) {
#pragma unroll
        for (int h = 0; h < 2; ++h) {
            int db = d0 + 32 * h;
            gload_lds16(Atb + (size_t)(s0 + wid * 32 + grow) * DIM + db + gcol, &As[h][wid * 1024]);
            gload_lds16(Ut  + (size_t)(e0 + wid * 32 + grow) * DIM + db + gcol, &Us[h][wid * 1024]);
        }
        __syncthreads();
#pragma unroll
        for (int h = 0; h < 2; ++h) {
            llong av[4], bv[4];
#pragma unroll
            for (int i = 0; i < 4; ++i)
                av[i] = *(const llong*)&As[h][(wr * 64 + 16 * i + l15) * 32 + quad * 8];
#pragma unroll
            for (int j = 0; j < 4; ++j)
                bv[j] = *(const llong*)&Us[h][(wc * 64 + 16 * j + l15) * 32 + quad * 8];
#pragma unroll
            for (int i = 0; i < 4; ++i)
#pragma unroll
                for (int j = 0; j < 4; ++j)
                    acc[i][j] = __builtin_amdgcn_mfma_f32_16x16x32_fp8_fp8(av[i], bv[j], acc[i][j], 0, 0, 0);
        }
        __syncthreads();
    }
    unsigned char* Cb = Ct + (size_t)b * SEQA * DIM;
#pragma unroll
    for (int i = 0; i < 4; ++i)
#pragma unroll
        for (int j = 0; j < 4; ++j) {
            int e_g = e0 + wc * 64 + 16 * j + l15;
#pragma unroll
            for (int r = 0; r < 4; ++r) {
                int s_g = s0 + wr * 64 + 16 * i + quad * 4 + r;
                Cb[(size_t)s_g * DIM + e_g] = f2fp8(acc[i][j][r]);
            }
        }
}

// ---- k2: tile = tanh(Ct Bt^T) + msk; fused row/col max -> atomic keys ----
__global__ __launch_bounds__(256) void k2_align(const unsigned char* __restrict__ Ct,
                                                const unsigned char* __restrict__ Bt,
                                                const float* __restrict__ msk,
                                                unsigned* __restrict__ keyA,
                                                unsigned* __restrict__ keyB) {
    __shared__ __align__(16) unsigned char Cs[2][4096];
    __shared__ __align__(16) unsigned char Bs[2][4096];
    const int b  = blockIdx.z;
    const int t0 = blockIdx.x * 128;
    const int s0 = blockIdx.y * 128;
    const int tid = threadIdx.x;
    const int lane = tid & 63;
    const int wid = tid >> 6;
    const int wr = wid >> 1, wc = wid & 1;
    const int quad = lane >> 4, l15 = lane & 15;
    const int grow = lane >> 1, gcol = (lane & 1) * 16;

    f32x4 acc[4][4] = {};

    for (int e0 = 0; e0 < DIM; e0 += 64) {
#pragma unroll
        for (int h = 0; h < 2; ++h) {
            int eb = e0 + 32 * h;
            gload_lds16(Ct + (size_t)(b * SEQA + s0 + wid * 32 + grow) * DIM + eb + gcol, &Cs[h][wid * 1024]);
            gload_lds16(Bt + (size_t)(b * SEQB + t0 + wid * 32 + grow) * DIM + eb + gcol, &Bs[h][wid * 1024]);
        }
        __syncthreads();
#pragma unroll
        for (int h = 0; h < 2; ++h) {
            llong av[4], bv[4];
#pragma unroll
            for (int i = 0; i < 4; ++i)
                av[i] = *(const llong*)&Cs[h][(wr * 64 + 16 * i + l15) * 32 + quad * 8];
#pragma unroll
            for (int j = 0; j < 4; ++j)
                bv[j] = *(const llong*)&Bs[h][(wc * 64 + 16 * j + l15) * 32 + quad * 8];
#pragma unroll
            for (int i = 0; i < 4; ++i)
#pragma unroll
                for (int j = 0; j < 4; ++j)
                    acc[i][j] = __builtin_amdgcn_mfma_f32_16x16x32_fp8_fp8(av[i], bv[j], acc[i][j], 0, 0, 0);
        }
        __syncthreads();
    }

    // epilogue: tanh + mask
    const float* Mb = msk + (size_t)b * SEQA * SEQB;
#pragma unroll
    for (int i = 0; i < 4; ++i)
#pragma unroll
        for (int j = 0; j < 4; ++j) {
            int t_g = t0 + wc * 64 + 16 * j + l15;
#pragma unroll
            for (int r = 0; r < 4; ++r) {
                int s_g = s0 + wr * 64 + 16 * i + quad * 4 + r;
                acc[i][j][r] = fast_tanh(acc[i][j][r]) + Mb[(size_t)s_g * SEQB + t_g];
            }
        }
    // row maxes (over t): in-lane over j, then across l15, atomic per row
#pragma unroll
    for (int i = 0; i < 4; ++i)
#pragma unroll
        for (int r = 0; r < 4; ++r) {
            float m = fmaxf(fmaxf(acc[i][0][r], acc[i][1][r]), fmaxf(acc[i][2][r], acc[i][3][r]));
            m = fmaxf(m, __shfl_xor(m, 1));
            m = fmaxf(m, __shfl_xor(m, 2));
            m = fmaxf(m, __shfl_xor(m, 4));
            m = fmaxf(m, __shfl_xor(m, 8));
            if (l15 == 0)
                atomicMax(&keyA[b * SEQA + s0 + wr * 64 + 16 * i + quad * 4 + r], enc_key(m));
        }
    // col maxes (over s): in-lane over i,r, then across quads
#pragma unroll
    for (int j = 0; j < 4; ++j) {
        float m = -INFINITY;
#pragma unroll
        for (int i = 0; i < 4; ++i)
#pragma unroll
            for (int r = 0; r < 4; ++r) m = fmaxf(m, acc[i][j][r]);
        m = fmaxf(m, __shfl_xor(m, 16));
        m = fmaxf(m, __shfl_xor(m, 32));
        if (quad == 0)
            atomicMax(&keyB[b * SEQB + t0 + wc * 64 + 16 * j + l15], enc_key(m));
    }
}

// ---- k3: softmax over per-token maxes ----
__global__ __launch_bounds__(256) void k3_softmax(const unsigned* __restrict__ keyA,
                                                  const unsigned* __restrict__ keyB,
                                                  float* __restrict__ scoreA,
                                                  float* __restrict__ scoreB) {
    const int b = blockIdx.x;
    const bool isA = (blockIdx.y == 0);
    const unsigned* keys = isA ? (keyA + b * SEQA) : (keyB + b * SEQB);
    float* score = isA ? (scoreA + b * SEQA) : (scoreB + b * SEQB);
    __shared__ float sh[4];
    const int tid = threadIdx.x;
    float m[4];
    float mx = -INFINITY;
#pragma unroll
    for (int k = 0; k < 4; k++) {
        m[k] = dec_key(keys[tid + 256 * k]);
        mx = fmaxf(mx, m[k]);
    }
#pragma unroll
    for (int o = 32; o > 0; o >>= 1) mx = fmaxf(mx, __shfl_down(mx, o, 64));
    if ((tid & 63) == 0) sh[tid >> 6] = mx;
    __syncthreads();
    mx = fmaxf(fmaxf(sh[0], sh[1]), fmaxf(sh[2], sh[3]));
    __syncthreads();
    float e[4];
    float sum = 0.f;
#pragma unroll
    for (int k = 0; k < 4; k++) { e[k] = expf(m[k] - mx); sum += e[k]; }
#pragma unroll
    for (int o = 32; o > 0; o >>= 1) sum += __shfl_down(sum, o, 64);
    if ((tid & 63) == 0) sh[tid >> 6] = sum;
    __syncthreads();
    sum = sh[0] + sh[1] + sh[2] + sh[3];
    float inv = 1.0f / sum;
#pragma unroll
    for (int k = 0; k < 4; k++) score[tid + 256 * k] = e[k] * inv;
}

// ---- k4: out[b,d] = sum_s X[b,d,s] * score[b,s]  (fp32, one wave per row) ----
__global__ __launch_bounds__(256) void k4_out(const float* __restrict__ A,
                                              const float* __restrict__ B,
                                              const float* __restrict__ scoreA,
                                              const float* __restrict__ scoreB,
                                              float* __restrict__ out) {
    const int which = blockIdx.y;
    const int row = blockIdx.x * 4 + (threadIdx.x >> 6);
    const int lane = threadIdx.x & 63;
    const float* X = which ? B : A;
    const float* S = which ? scoreB : scoreA;
    const int b = row / DIM;
    const float4* xr = (const float4*)(X + (size_t)row * SEQA);
    const float4* sr = (const float4*)(S + (size_t)b * SEQA);
    float acc = 0.f;
#pragma unroll
    for (int q = lane; q < SEQA / 4; q += 64) {
        float4 x = xr[q];
        float4 s = sr[q];
        acc += x.x * s.x + x.y * s.y + x.z * s.z + x.w * s.w;
    }
#pragma unroll
    for (int o = 32; o > 0; o >>= 1) acc += __shfl_down(acc, o, 64);
    if (lane == 0) out[which * (BSZ * DIM) + row] = acc;
}

extern "C" void kernel_launch(void* const* d_in, const int* in_sizes, int n_in,
                              void* d_out, int out_size, void* d_ws, size_t ws_size,
                              hipStream_t stream) {
    const float* A   = (const float*)d_in[0];  // (16,768,1024)
    const float* B   = (const float*)d_in[1];  // (16,768,1024)
    const float* msk = (const float*)d_in[2];  // (16,1024,1024)
    const float* U   = (const float*)d_in[3];  // (768,768)
    float* out = (float*)d_out;

    // workspace layout (fp8 operands): total ~38.7 MB (round-2 proved >=51.7 MB available)
    char* ws = (char*)d_ws;
    unsigned char* At = (unsigned char*)ws;                   // 16*1024*768 = 12,582,912
    unsigned char* Bt = (unsigned char*)(ws + 12582912);      // 12,582,912
    unsigned char* Ct = (unsigned char*)(ws + 25165824);      // 12,582,912
    unsigned char* Ut = (unsigned char*)(ws + 37748736);      //    589,824
    unsigned* keyA   = (unsigned*)(ws + 38338560);
    unsigned* keyB   = (unsigned*)(ws + 38404096);
    float*    scoreA = (float*)   (ws + 38469632);
    float*    scoreB = (float*)   (ws + 38535168);

    t_cast_U<<<dim3(DIM / 64, DIM / 64, 1), 256, 0, stream>>>(U, Ut, keyA, keyB);
    t_cast_AB<<<dim3(SEQA / 64, DIM / 64, 2 * BSZ), 256, 0, stream>>>(A, B, At, Bt);
    k1_ua<<<dim3(SEQA / 128, DIM / 128, BSZ), 256, 0, stream>>>(At, Ut, Ct);
    k2_align<<<dim3(SEQB / 128, SEQA / 128, BSZ), 256, 0, stream>>>(Ct, Bt, msk, keyA, keyB);
    k3_softmax<<<dim3(BSZ, 2), 256, 0, stream>>>(keyA, keyB, scoreA, scoreB);
    k4_out<<<dim3(BSZ * DIM / 4, 2), 256, 0, stream>>>(A, B, scoreA, scoreB, out);
}

// Round 4
// 257.110 us; speedup vs baseline: 3.5159x; 1.0106x over previous
//
#include <hip/hip_runtime.h>
#include <math.h>

#define BSZ  16
#define DIM  768
#define SEQA 1024
#define SEQB 1024

typedef float f32x4 __attribute__((ext_vector_type(4)));
typedef long long llong;

__device__ inline void gload_lds16(const void* g, void* l) {
    __builtin_amdgcn_global_load_lds(
        (const __attribute__((address_space(1))) void*)g,
        (__attribute__((address_space(3))) void*)l, 16, 0, 0);
}

// ---- float <-> order-preserving uint key (atomicMax on floats) ----
__device__ inline unsigned enc_key(float f) {
    unsigned u = __float_as_uint(f);
    return (u & 0x80000000u) ? ~u : (u | 0x80000000u);
}
__device__ inline float dec_key(unsigned k) {
    return (k & 0x80000000u) ? __uint_as_float(k ^ 0x80000000u) : __uint_as_float(~k);
}

// ---- fp8 e4m3 (OCP) pack helpers ----
__device__ inline unsigned pk4_fp8(float a, float b, float c, float d) {
    int v = 0;
    v = __builtin_amdgcn_cvt_pk_fp8_f32(a, b, v, false);
    v = __builtin_amdgcn_cvt_pk_fp8_f32(c, d, v, true);
    return (unsigned)v;
}

// tanh via hardware exp: exact 1.0f in saturation, ~1e-6 error mid-range
__device__ inline float fast_tanh(float x) {
    float ax = fabsf(x);
    float u = __expf(-2.0f * ax);
    float th = __fdividef(1.0f - u, 1.0f + u);
    return copysignf(th, x);
}

// ---- prepass: X[b][DIM][SEQ] f32 -> Xt[b][SEQ][DIM] fp8 for A (z<16) and B (z>=16) ----
__global__ __launch_bounds__(256) void t_cast_AB(const float* __restrict__ A,
                                                 const float* __restrict__ B,
                                                 unsigned char* __restrict__ At,
                                                 unsigned char* __restrict__ Bt) {
    __shared__ float tl[64][65];
    const int z = blockIdx.z;
    const float* X = (z < BSZ) ? A : B;
    unsigned char* Y = (z < BSZ) ? At : Bt;
    const int b = z & 15;
    const int d0 = blockIdx.y * 64;
    const int s0 = blockIdx.x * 64;
    const int tid = threadIdx.x;
    const int c = tid & 63, r4 = tid >> 6;
    const float* Xb = X + ((size_t)b * DIM + d0) * SEQA + s0;
#pragma unroll
    for (int i = 0; i < 64; i += 4)
        tl[i + r4][c] = Xb[(size_t)(i + r4) * SEQA + c];
    __syncthreads();
    unsigned char* Yb = Y + ((size_t)b * SEQA + s0) * DIM + d0;
    const int m = tid & 15, sl = tid >> 4;
#pragma unroll
    for (int i = 0; i < 4; i++) {
        int s = sl + 16 * i;
        unsigned v = pk4_fp8(tl[4 * m + 0][s], tl[4 * m + 1][s], tl[4 * m + 2][s], tl[4 * m + 3][s]);
        *(unsigned*)&Yb[(size_t)s * DIM + 4 * m] = v;
    }
}

// ---- prepass: U[d][e] f32 -> Ut[e][d] fp8 ; also init max-keys ----
__global__ __launch_bounds__(256) void t_cast_U(const float* __restrict__ U,
                                                unsigned char* __restrict__ Ut,
                                                unsigned* __restrict__ keyA,
                                                unsigned* __restrict__ keyB) {
    __shared__ float tl[64][65];
    const int d0 = blockIdx.y * 64;
    const int e0 = blockIdx.x * 64;
    const int tid = threadIdx.x;
    const int bid = blockIdx.y * gridDim.x + blockIdx.x;
    if (bid < 64) {
        int i = bid * 256 + tid;
        keyA[i] = 0u;
        keyB[i] = 0u;
    }
    const int c = tid & 63, r4 = tid >> 6;
#pragma unroll
    for (int i = 0; i < 64; i += 4)
        tl[i + r4][c] = U[(size_t)(d0 + i + r4) * DIM + e0 + c];
    __syncthreads();
    const int m = tid & 15, sl = tid >> 4;
#pragma unroll
    for (int i = 0; i < 4; i++) {
        int e = sl + 16 * i;
        unsigned v = pk4_fp8(tl[4 * m + 0][e], tl[4 * m + 1][e], tl[4 * m + 2][e], tl[4 * m + 3][e]);
        *(unsigned*)&Ut[(size_t)(e0 + e) * DIM + d0 + 4 * m] = v;
    }
}

// ---- k1: Ct[b][s][e] = sum_d At[b][s][d] * Ut[e][d]  (fp8 MFMA, 128x128, BK=64) ----
// Operand order: A-side = Ut (M=e), B-side = At (N=s)  -> lane owns 4 consecutive e.
__global__ __launch_bounds__(256) void k1_ua(const unsigned char* __restrict__ At,
                                             const unsigned char* __restrict__ Ut,
                                             unsigned char* __restrict__ Ct) {
    __shared__ __align__(16) unsigned char As[2][4096];
    __shared__ __align__(16) unsigned char Us[2][4096];
    const int b  = blockIdx.z;
    const int s0 = blockIdx.x * 128;
    const int e0 = blockIdx.y * 128;
    const int tid = threadIdx.x;
    const int lane = tid & 63;
    const int wid = tid >> 6;
    const int wr = wid >> 1, wc = wid & 1;
    const int quad = lane >> 4, l15 = lane & 15;
    // swizzled staging: lane stages row=lane>>1, k-granule=(lane&1)^((lane>>3)&1)
    const int grow = lane >> 1;
    const int gcol = ((lane & 1) ^ ((lane >> 3) & 1)) * 16;
    // swizzled fragment-read k-offset
    const int koff = (((quad >> 1) ^ ((l15 >> 2) & 1)) << 4) + (quad & 1) * 8;

    const unsigned char* Atb = At + (size_t)b * SEQA * DIM;
    f32x4 acc[4][4] = {};

    for (int d0 = 0; d0 < DIM; d0 += 64) {
#pragma unroll
        for (int h = 0; h < 2; ++h) {
            int db = d0 + 32 * h;
            gload_lds16(Atb + (size_t)(s0 + wid * 32 + grow) * DIM + db + gcol, &As[h][wid * 1024]);
            gload_lds16(Ut  + (size_t)(e0 + wid * 32 + grow) * DIM + db + gcol, &Us[h][wid * 1024]);
        }
        __syncthreads();
#pragma unroll
        for (int h = 0; h < 2; ++h) {
            llong av[4], bv[4];
#pragma unroll
            for (int i = 0; i < 4; ++i)
                av[i] = *(const llong*)&Us[h][(wr * 64 + 16 * i + l15) * 32 + koff];
#pragma unroll
            for (int j = 0; j < 4; ++j)
                bv[j] = *(const llong*)&As[h][(wc * 64 + 16 * j + l15) * 32 + koff];
#pragma unroll
            for (int i = 0; i < 4; ++i)
#pragma unroll
                for (int j = 0; j < 4; ++j)
                    acc[i][j] = __builtin_amdgcn_mfma_f32_16x16x32_fp8_fp8(av[i], bv[j], acc[i][j], 0, 0, 0);
        }
        __syncthreads();
    }
    // D layout: M(e) = wr*64+16i+quad*4+r (4 consecutive e in-lane), N(s) = wc*64+16j+l15
    unsigned char* Cb = Ct + (size_t)b * SEQA * DIM;
#pragma unroll
    for (int i = 0; i < 4; ++i)
#pragma unroll
        for (int j = 0; j < 4; ++j) {
            int e_g = e0 + wr * 64 + 16 * i + quad * 4;
            int s_g = s0 + wc * 64 + 16 * j + l15;
            unsigned v = pk4_fp8(acc[i][j][0], acc[i][j][1], acc[i][j][2], acc[i][j][3]);
            *(unsigned*)&Cb[(size_t)s_g * DIM + e_g] = v;
        }
}

// ---- k2: align^T tile = tanh(Bt-tile x Ct-tile) + msk; fused max -> atomic keys ----
// Operand order: A-side = Bt (M=t), B-side = Ct (N=s) -> lane owns 4 consecutive t -> float4 mask.
__global__ __launch_bounds__(256) void k2_align(const unsigned char* __restrict__ Ct,
                                                const unsigned char* __restrict__ Bt,
                                                const float* __restrict__ msk,
                                                unsigned* __restrict__ keyA,
                                                unsigned* __restrict__ keyB) {
    __shared__ __align__(16) unsigned char Cs[2][4096];
    __shared__ __align__(16) unsigned char Bs[2][4096];
    const int b  = blockIdx.x;
    const int t0 = blockIdx.y * 128;
    const int s0 = blockIdx.z * 128;
    const int tid = threadIdx.x;
    const int lane = tid & 63;
    const int wid = tid >> 6;
    const int wr = wid >> 1, wc = wid & 1;
    const int quad = lane >> 4, l15 = lane & 15;
    const int grow = lane >> 1;
    const int gcol = ((lane & 1) ^ ((lane >> 3) & 1)) * 16;
    const int koff = (((quad >> 1) ^ ((l15 >> 2) & 1)) << 4) + (quad & 1) * 8;

    f32x4 acc[4][4] = {};

    for (int e0 = 0; e0 < DIM; e0 += 64) {
#pragma unroll
        for (int h = 0; h < 2; ++h) {
            int eb = e0 + 32 * h;
            gload_lds16(Ct + (size_t)(b * SEQA + s0 + wid * 32 + grow) * DIM + eb + gcol, &Cs[h][wid * 1024]);
            gload_lds16(Bt + (size_t)(b * SEQB + t0 + wid * 32 + grow) * DIM + eb + gcol, &Bs[h][wid * 1024]);
        }
        __syncthreads();
#pragma unroll
        for (int h = 0; h < 2; ++h) {
            llong av[4], bv[4];
#pragma unroll
            for (int i = 0; i < 4; ++i)
                av[i] = *(const llong*)&Bs[h][(wr * 64 + 16 * i + l15) * 32 + koff];
#pragma unroll
            for (int j = 0; j < 4; ++j)
                bv[j] = *(const llong*)&Cs[h][(wc * 64 + 16 * j + l15) * 32 + koff];
#pragma unroll
            for (int i = 0; i < 4; ++i)
#pragma unroll
                for (int j = 0; j < 4; ++j)
                    acc[i][j] = __builtin_amdgcn_mfma_f32_16x16x32_fp8_fp8(av[i], bv[j], acc[i][j], 0, 0, 0);
        }
        __syncthreads();
    }

    // D layout: M(t) = wr*64+16i+quad*4+r, N(s) = wc*64+16j+l15
    const float* Mb = msk + (size_t)b * SEQA * SEQB;
#pragma unroll
    for (int i = 0; i < 4; ++i)
#pragma unroll
        for (int j = 0; j < 4; ++j) {
            int s_g = s0 + wc * 64 + 16 * j + l15;
            int t_g = t0 + wr * 64 + 16 * i + quad * 4;
            float4 mv = *(const float4*)&Mb[(size_t)s_g * SEQB + t_g];
            acc[i][j][0] = fast_tanh(acc[i][j][0]) + mv.x;
            acc[i][j][1] = fast_tanh(acc[i][j][1]) + mv.y;
            acc[i][j][2] = fast_tanh(acc[i][j][2]) + mv.z;
            acc[i][j][3] = fast_tanh(acc[i][j][3]) + mv.w;
        }
    // keyA[s]: max over t  (in-lane i,r; cross-quad)
#pragma unroll
    for (int j = 0; j < 4; ++j) {
        float m = -INFINITY;
#pragma unroll
        for (int i = 0; i < 4; ++i)
#pragma unroll
            for (int r = 0; r < 4; ++r) m = fmaxf(m, acc[i][j][r]);
        m = fmaxf(m, __shfl_xor(m, 16));
        m = fmaxf(m, __shfl_xor(m, 32));
        if (quad == 0)
            atomicMax(&keyA[b * SEQA + s0 + wc * 64 + 16 * j + l15], enc_key(m));
    }
    // keyB[t]: max over s  (in-lane j; cross-l15)
#pragma unroll
    for (int i = 0; i < 4; ++i)
#pragma unroll
        for (int r = 0; r < 4; ++r) {
            float m = fmaxf(fmaxf(acc[i][0][r], acc[i][1][r]), fmaxf(acc[i][2][r], acc[i][3][r]));
            m = fmaxf(m, __shfl_xor(m, 1));
            m = fmaxf(m, __shfl_xor(m, 2));
            m = fmaxf(m, __shfl_xor(m, 4));
            m = fmaxf(m, __shfl_xor(m, 8));
            if (l15 == 0)
                atomicMax(&keyB[b * SEQB + t0 + wr * 64 + 16 * i + quad * 4 + r], enc_key(m));
        }
}

// ---- k3: softmax over per-token maxes ----
__global__ __launch_bounds__(256) void k3_softmax(const unsigned* __restrict__ keyA,
                                                  const unsigned* __restrict__ keyB,
                                                  float* __restrict__ scoreA,
                                                  float* __restrict__ scoreB) {
    const int b = blockIdx.x;
    const bool isA = (blockIdx.y == 0);
    const unsigned* keys = isA ? (keyA + b * SEQA) : (keyB + b * SEQB);
    float* score = isA ? (scoreA + b * SEQA) : (scoreB + b * SEQB);
    __shared__ float sh[4];
    const int tid = threadIdx.x;
    float m[4];
    float mx = -INFINITY;
#pragma unroll
    for (int k = 0; k < 4; k++) {
        m[k] = dec_key(keys[tid + 256 * k]);
        mx = fmaxf(mx, m[k]);
    }
#pragma unroll
    for (int o = 32; o > 0; o >>= 1) mx = fmaxf(mx, __shfl_down(mx, o, 64));
    if ((tid & 63) == 0) sh[tid >> 6] = mx;
    __syncthreads();
    mx = fmaxf(fmaxf(sh[0], sh[1]), fmaxf(sh[2], sh[3]));
    __syncthreads();
    float e[4];
    float sum = 0.f;
#pragma unroll
    for (int k = 0; k < 4; k++) { e[k] = expf(m[k] - mx); sum += e[k]; }
#pragma unroll
    for (int o = 32; o > 0; o >>= 1) sum += __shfl_down(sum, o, 64);
    if ((tid & 63) == 0) sh[tid >> 6] = sum;
    __syncthreads();
    sum = sh[0] + sh[1] + sh[2] + sh[3];
    float inv = 1.0f / sum;
#pragma unroll
    for (int k = 0; k < 4; k++) score[tid + 256 * k] = e[k] * inv;
}

// ---- k4: out[b,d] = sum_s X[b,d,s] * score[b,s]  (fp32, one wave per row) ----
__global__ __launch_bounds__(256) void k4_out(const float* __restrict__ A,
                                              const float* __restrict__ B,
                                              const float* __restrict__ scoreA,
                                              const float* __restrict__ scoreB,
                                              float* __restrict__ out) {
    const int which = blockIdx.y;
    const int row = blockIdx.x * 4 + (threadIdx.x >> 6);
    const int lane = threadIdx.x & 63;
    const float* X = which ? B : A;
    const float* S = which ? scoreB : scoreA;
    const int b = row / DIM;
    const float4* xr = (const float4*)(X + (size_t)row * SEQA);
    const float4* sr = (const float4*)(S + (size_t)b * SEQA);
    float acc = 0.f;
#pragma unroll
    for (int q = lane; q < SEQA / 4; q += 64) {
        float4 x = xr[q];
        float4 s = sr[q];
        acc += x.x * s.x + x.y * s.y + x.z * s.z + x.w * s.w;
    }
#pragma unroll
    for (int o = 32; o > 0; o >>= 1) acc += __shfl_down(acc, o, 64);
    if (lane == 0) out[which * (BSZ * DIM) + row] = acc;
}

extern "C" void kernel_launch(void* const* d_in, const int* in_sizes, int n_in,
                              void* d_out, int out_size, void* d_ws, size_t ws_size,
                              hipStream_t stream) {
    const float* A   = (const float*)d_in[0];  // (16,768,1024)
    const float* B   = (const float*)d_in[1];  // (16,768,1024)
    const float* msk = (const float*)d_in[2];  // (16,1024,1024)
    const float* U   = (const float*)d_in[3];  // (768,768)
    float* out = (float*)d_out;

    char* ws = (char*)d_ws;
    unsigned char* At = (unsigned char*)ws;                   // 12,582,912
    unsigned char* Bt = (unsigned char*)(ws + 12582912);      // 12,582,912
    unsigned char* Ct = (unsigned char*)(ws + 25165824);      // 12,582,912
    unsigned char* Ut = (unsigned char*)(ws + 37748736);      //    589,824
    unsigned* keyA   = (unsigned*)(ws + 38338560);
    unsigned* keyB   = (unsigned*)(ws + 38404096);
    float*    scoreA = (float*)   (ws + 38469632);
    float*    scoreB = (float*)   (ws + 38535168);

    t_cast_U<<<dim3(DIM / 64, DIM / 64, 1), 256, 0, stream>>>(U, Ut, keyA, keyB);
    t_cast_AB<<<dim3(SEQA / 64, DIM / 64, 2 * BSZ), 256, 0, stream>>>(A, B, At, Bt);
    k1_ua<<<dim3(SEQA / 128, DIM / 128, BSZ), 256, 0, stream>>>(At, Ut, Ct);
    k2_align<<<dim3(BSZ, SEQB / 128, SEQA / 128), 256, 0, stream>>>(Ct, Bt, msk, keyA, keyB);
    k3_softmax<<<dim3(BSZ, 2), 256, 0, stream>>>(keyA, keyB, scoreA, scoreB);
    k4_out<<<dim3(BSZ * DIM / 4, 2), 256, 0, stream>>>(A, B, scoreA, scoreB, out);
}

// Round 5
// 245.866 us; speedup vs baseline: 3.6766x; 1.0457x over previous
//
#include <hip/hip_runtime.h>
#include <math.h>

#define BSZ  16
#define DIM  768
#define SEQA 1024
#define SEQB 1024

typedef float f32x4 __attribute__((ext_vector_type(4)));
typedef long long llong;

__device__ inline void gload_lds16(const void* g, void* l) {
    __builtin_amdgcn_global_load_lds(
        (const __attribute__((address_space(1))) void*)g,
        (__attribute__((address_space(3))) void*)l, 16, 0, 0);
}

// ---- float <-> order-preserving uint key (atomicMax on floats) ----
__device__ inline unsigned enc_key(float f) {
    unsigned u = __float_as_uint(f);
    return (u & 0x80000000u) ? ~u : (u | 0x80000000u);
}
__device__ inline float dec_key(unsigned k) {
    return (k & 0x80000000u) ? __uint_as_float(k ^ 0x80000000u) : __uint_as_float(~k);
}

// ---- fp8 e4m3 (OCP) pack helpers ----
__device__ inline unsigned pk4_fp8(float a, float b, float c, float d) {
    int v = 0;
    v = __builtin_amdgcn_cvt_pk_fp8_f32(a, b, v, false);
    v = __builtin_amdgcn_cvt_pk_fp8_f32(c, d, v, true);
    return (unsigned)v;
}
__device__ inline unsigned char f2fp8(float a) {
    return (unsigned char)(__builtin_amdgcn_cvt_pk_fp8_f32(a, a, 0, false) & 0xFF);
}

// tanh via hardware exp: exact 1.0f in saturation, ~1e-6 error mid-range
__device__ inline float fast_tanh(float x) {
    float ax = fabsf(x);
    float u = __expf(-2.0f * ax);
    float th = __fdividef(1.0f - u, 1.0f + u);
    return copysignf(th, x);
}

// ---- prepass: X[b][DIM][SEQ] f32 -> Xt[b][SEQ][DIM] fp8 for A (z<16) and B (z>=16) ----
__global__ __launch_bounds__(256) void t_cast_AB(const float* __restrict__ A,
                                                 const float* __restrict__ B,
                                                 unsigned char* __restrict__ At,
                                                 unsigned char* __restrict__ Bt) {
    __shared__ float tl[64][68];
    const int z = blockIdx.z;
    const float* X = (z < BSZ) ? A : B;
    unsigned char* Y = (z < BSZ) ? At : Bt;
    const int b = z & 15;
    const int d0 = blockIdx.y * 64;
    const int s0 = blockIdx.x * 64;
    const int tid = threadIdx.x;
    const int rr = tid >> 4, c4 = tid & 15;  // float4 loader coords
    const float* Xb = X + ((size_t)b * DIM + d0) * SEQA + s0;
#pragma unroll
    for (int i = 0; i < 4; i++) {
        int row = i * 16 + rr;
        float4 v = *(const float4*)&Xb[(size_t)row * SEQA + c4 * 4];
        *(float4*)&tl[row][c4 * 4] = v;
    }
    __syncthreads();
    unsigned char* Yb = Y + ((size_t)b * SEQA + s0) * DIM + d0;
    const int m = tid & 15, sl = tid >> 4;
#pragma unroll
    for (int i = 0; i < 4; i++) {
        int s = sl + 16 * i;
        unsigned v = pk4_fp8(tl[4 * m + 0][s], tl[4 * m + 1][s], tl[4 * m + 2][s], tl[4 * m + 3][s]);
        *(unsigned*)&Yb[(size_t)s * DIM + 4 * m] = v;
    }
}

// ---- prepass: U[d][e] f32 -> Ut[e][d] fp8 ; also init max-keys ----
__global__ __launch_bounds__(256) void t_cast_U(const float* __restrict__ U,
                                                unsigned char* __restrict__ Ut,
                                                unsigned* __restrict__ keyA,
                                                unsigned* __restrict__ keyB) {
    __shared__ float tl[64][68];
    const int d0 = blockIdx.y * 64;
    const int e0 = blockIdx.x * 64;
    const int tid = threadIdx.x;
    const int bid = blockIdx.y * gridDim.x + blockIdx.x;
    if (bid < 64) {
        int i = bid * 256 + tid;
        keyA[i] = 0u;
        keyB[i] = 0u;
    }
    const int rr = tid >> 4, c4 = tid & 15;
#pragma unroll
    for (int i = 0; i < 4; i++) {
        int row = i * 16 + rr;
        float4 v = *(const float4*)&U[(size_t)(d0 + row) * DIM + e0 + c4 * 4];
        *(float4*)&tl[row][c4 * 4] = v;
    }
    __syncthreads();
    const int m = tid & 15, sl = tid >> 4;
#pragma unroll
    for (int i = 0; i < 4; i++) {
        int e = sl + 16 * i;
        unsigned v = pk4_fp8(tl[4 * m + 0][e], tl[4 * m + 1][e], tl[4 * m + 2][e], tl[4 * m + 3][e]);
        *(unsigned*)&Ut[(size_t)(e0 + e) * DIM + d0 + 4 * m] = v;
    }
}

// Stage one 128x128-byte tile (rows of `src` pitch DIM) into LDS with granule-XOR
// swizzle. Wave `wid` covers rows [wid*32, wid*32+32).
__device__ inline void stage_tile(const unsigned char* __restrict__ src, int row0,
                                  int kbyte0, unsigned char* lds, int wid, int lane) {
    const int r8 = lane >> 3;              // row within 8-row group
    const int g  = lane & 7;               // dest granule slot
    const int gg = g ^ (r8 & 7);           // source granule (XOR swizzle)
#pragma unroll
    for (int t = 0; t < 4; ++t) {
        int row = row0 + wid * 32 + t * 8 + r8;
        gload_lds16(src + (size_t)row * DIM + kbyte0 + gg * 16,
                    lds + (wid * 32 + t * 8) * 128 + lane * 16);
    }
}

// Read an 8-byte fp8 fragment (16 rows x k-slice) with matching XOR un-swizzle.
// rowbase multiple of 16; h = 32-byte k-slice index (0..3).
__device__ inline llong frag_read(const unsigned char* lds, int rowbase, int l15,
                                  int quad, int h) {
    int gg = 2 * h + (quad >> 1);
    int off = (rowbase + l15) * 128 + ((gg ^ (l15 & 7)) << 4) + (quad & 1) * 8;
    return *(const llong*)(lds + off);
}

// ---- k1: Ct[b][s][e] = sum_d At[b][s][d] * Ut[e][d]  (fp8 MFMA, 128x128, BK=128) ----
// A-side = At (M=s), B-side = Ut (N=e): lane's D row-quad = 4 consecutive s; e on l15.
__global__ __launch_bounds__(256) void k1_ua(const unsigned char* __restrict__ At,
                                             const unsigned char* __restrict__ Ut,
                                             unsigned char* __restrict__ Ct) {
    __shared__ __align__(16) unsigned char As[128 * 128];
    __shared__ __align__(16) unsigned char Us[128 * 128];
    const int b  = blockIdx.z;
    const int s0 = blockIdx.x * 128;
    const int e0 = blockIdx.y * 128;
    const int tid = threadIdx.x;
    const int lane = tid & 63;
    const int wid = tid >> 6;
    const int wr = wid >> 1, wc = wid & 1;
    const int quad = lane >> 4, l15 = lane & 15;

    const unsigned char* Atb = At + (size_t)b * SEQA * DIM;
    f32x4 acc[4][4] = {};

    for (int d0 = 0; d0 < DIM; d0 += 128) {
        stage_tile(Atb + (size_t)s0 * DIM, 0, d0, As, wid, lane);
        stage_tile(Ut + (size_t)e0 * DIM, 0, d0, Us, wid, lane);
        __syncthreads();
#pragma unroll
        for (int h = 0; h < 4; ++h) {
            llong av[4], bv[4];
#pragma unroll
            for (int i = 0; i < 4; ++i) av[i] = frag_read(As, wr * 64 + 16 * i, l15, quad, h);
#pragma unroll
            for (int j = 0; j < 4; ++j) bv[j] = frag_read(Us, wc * 64 + 16 * j, l15, quad, h);
#pragma unroll
            for (int i = 0; i < 4; ++i)
#pragma unroll
                for (int j = 0; j < 4; ++j)
                    acc[i][j] = __builtin_amdgcn_mfma_f32_16x16x32_fp8_fp8(av[i], bv[j], acc[i][j], 0, 0, 0);
        }
        __syncthreads();
    }
    // D: M(s) = wr*64+16i+quad*4+r, N(e) = wc*64+16j+l15 -> byte stores, 16B segments
    unsigned char* Cb = Ct + (size_t)b * SEQA * DIM;
#pragma unroll
    for (int i = 0; i < 4; ++i)
#pragma unroll
        for (int j = 0; j < 4; ++j) {
            int e_g = e0 + wc * 64 + 16 * j + l15;
#pragma unroll
            for (int r = 0; r < 4; ++r) {
                int s_g = s0 + wr * 64 + 16 * i + quad * 4 + r;
                Cb[(size_t)s_g * DIM + e_g] = f2fp8(acc[i][j][r]);
            }
        }
}

// ---- k2: align^T tile = tanh(Bt x Ct) + msk; fused max -> atomic keys ----
// A-side = Bt (M=t), B-side = Ct (N=s): lane's D row-quad = 4 consecutive t -> float4 mask.
__global__ __launch_bounds__(256, 2) void k2_align(const unsigned char* __restrict__ Ct,
                                                   const unsigned char* __restrict__ Bt,
                                                   const float* __restrict__ msk,
                                                   unsigned* __restrict__ keyA,
                                                   unsigned* __restrict__ keyB) {
    __shared__ __align__(16) unsigned char Cs[128 * 128];
    __shared__ __align__(16) unsigned char Bs[128 * 128];
    const int b  = blockIdx.z;
    const int t0 = blockIdx.x * 128;
    const int s0 = blockIdx.y * 128;
    const int tid = threadIdx.x;
    const int lane = tid & 63;
    const int wid = tid >> 6;
    const int wr = wid >> 1, wc = wid & 1;
    const int quad = lane >> 4, l15 = lane & 15;

    // prefetch mask (HBM) into VGPRs; drained by first K-loop barrier
    const float* Mb = msk + (size_t)b * SEQA * SEQB;
    float4 mv[4][4];
#pragma unroll
    for (int i = 0; i < 4; ++i)
#pragma unroll
        for (int j = 0; j < 4; ++j) {
            int s_g = s0 + wc * 64 + 16 * j + l15;
            int t_g = t0 + wr * 64 + 16 * i + quad * 4;
            mv[i][j] = *(const float4*)&Mb[(size_t)s_g * SEQB + t_g];
        }

    f32x4 acc[4][4] = {};

    for (int e0 = 0; e0 < DIM; e0 += 128) {
        stage_tile(Ct + (size_t)(b * SEQA + s0) * DIM, 0, e0, Cs, wid, lane);
        stage_tile(Bt + (size_t)(b * SEQB + t0) * DIM, 0, e0, Bs, wid, lane);
        __syncthreads();
#pragma unroll
        for (int h = 0; h < 4; ++h) {
            llong av[4], bv[4];
#pragma unroll
            for (int i = 0; i < 4; ++i) av[i] = frag_read(Bs, wr * 64 + 16 * i, l15, quad, h);
#pragma unroll
            for (int j = 0; j < 4; ++j) bv[j] = frag_read(Cs, wc * 64 + 16 * j, l15, quad, h);
#pragma unroll
            for (int i = 0; i < 4; ++i)
#pragma unroll
                for (int j = 0; j < 4; ++j)
                    acc[i][j] = __builtin_amdgcn_mfma_f32_16x16x32_fp8_fp8(av[i], bv[j], acc[i][j], 0, 0, 0);
        }
        __syncthreads();
    }

    // epilogue: tanh + prefetched mask
#pragma unroll
    for (int i = 0; i < 4; ++i)
#pragma unroll
        for (int j = 0; j < 4; ++j) {
            acc[i][j][0] = fast_tanh(acc[i][j][0]) + mv[i][j].x;
            acc[i][j][1] = fast_tanh(acc[i][j][1]) + mv[i][j].y;
            acc[i][j][2] = fast_tanh(acc[i][j][2]) + mv[i][j].z;
            acc[i][j][3] = fast_tanh(acc[i][j][3]) + mv[i][j].w;
        }
    // keyA[s]: max over t (in-lane i,r; cross-quad)
#pragma unroll
    for (int j = 0; j < 4; ++j) {
        float m = -INFINITY;
#pragma unroll
        for (int i = 0; i < 4; ++i)
#pragma unroll
            for (int r = 0; r < 4; ++r) m = fmaxf(m, acc[i][j][r]);
        m = fmaxf(m, __shfl_xor(m, 16));
        m = fmaxf(m, __shfl_xor(m, 32));
        if (quad == 0)
            atomicMax(&keyA[b * SEQA + s0 + wc * 64 + 16 * j + l15], enc_key(m));
    }
    // keyB[t]: max over s (in-lane j; cross-l15)
#pragma unroll
    for (int i = 0; i < 4; ++i)
#pragma unroll
        for (int r = 0; r < 4; ++r) {
            float m = fmaxf(fmaxf(acc[i][0][r], acc[i][1][r]), fmaxf(acc[i][2][r], acc[i][3][r]));
            m = fmaxf(m, __shfl_xor(m, 1));
            m = fmaxf(m, __shfl_xor(m, 2));
            m = fmaxf(m, __shfl_xor(m, 4));
            m = fmaxf(m, __shfl_xor(m, 8));
            if (l15 == 0)
                atomicMax(&keyB[b * SEQB + t0 + wr * 64 + 16 * i + quad * 4 + r], enc_key(m));
        }
}

// ---- k3: softmax over per-token maxes ----
__global__ __launch_bounds__(256) void k3_softmax(const unsigned* __restrict__ keyA,
                                                  const unsigned* __restrict__ keyB,
                                                  float* __restrict__ scoreA,
                                                  float* __restrict__ scoreB) {
    const int b = blockIdx.x;
    const bool isA = (blockIdx.y == 0);
    const unsigned* keys = isA ? (keyA + b * SEQA) : (keyB + b * SEQB);
    float* score = isA ? (scoreA + b * SEQA) : (scoreB + b * SEQB);
    __shared__ float sh[4];
    const int tid = threadIdx.x;
    float m[4];
    float mx = -INFINITY;
#pragma unroll
    for (int k = 0; k < 4; k++) {
        m[k] = dec_key(keys[tid + 256 * k]);
        mx = fmaxf(mx, m[k]);
    }
#pragma unroll
    for (int o = 32; o > 0; o >>= 1) mx = fmaxf(mx, __shfl_down(mx, o, 64));
    if ((tid & 63) == 0) sh[tid >> 6] = mx;
    __syncthreads();
    mx = fmaxf(fmaxf(sh[0], sh[1]), fmaxf(sh[2], sh[3]));
    __syncthreads();
    float e[4];
    float sum = 0.f;
#pragma unroll
    for (int k = 0; k < 4; k++) { e[k] = expf(m[k] - mx); sum += e[k]; }
#pragma unroll
    for (int o = 32; o > 0; o >>= 1) sum += __shfl_down(sum, o, 64);
    if ((tid & 63) == 0) sh[tid >> 6] = sum;
    __syncthreads();
    sum = sh[0] + sh[1] + sh[2] + sh[3];
    float inv = 1.0f / sum;
#pragma unroll
    for (int k = 0; k < 4; k++) score[tid + 256 * k] = e[k] * inv;
}

// ---- k4: out[b,d] = sum_s X[b,d,s] * score[b,s]  (fp32, one wave per row) ----
__global__ __launch_bounds__(256) void k4_out(const float* __restrict__ A,
                                              const float* __restrict__ B,
                                              const float* __restrict__ scoreA,
                                              const float* __restrict__ scoreB,
                                              float* __restrict__ out) {
    const int which = blockIdx.y;
    const int row = blockIdx.x * 4 + (threadIdx.x >> 6);
    const int lane = threadIdx.x & 63;
    const float* X = which ? B : A;
    const float* S = which ? scoreB : scoreA;
    const int b = row / DIM;
    const float4* xr = (const float4*)(X + (size_t)row * SEQA);
    const float4* sr = (const float4*)(S + (size_t)b * SEQA);
    float acc = 0.f;
#pragma unroll
    for (int q = lane; q < SEQA / 4; q += 64) {
        float4 x = xr[q];
        float4 s = sr[q];
        acc += x.x * s.x + x.y * s.y + x.z * s.z + x.w * s.w;
    }
#pragma unroll
    for (int o = 32; o > 0; o >>= 1) acc += __shfl_down(acc, o, 64);
    if (lane == 0) out[which * (BSZ * DIM) + row] = acc;
}

extern "C" void kernel_launch(void* const* d_in, const int* in_sizes, int n_in,
                              void* d_out, int out_size, void* d_ws, size_t ws_size,
                              hipStream_t stream) {
    const float* A   = (const float*)d_in[0];  // (16,768,1024)
    const float* B   = (const float*)d_in[1];  // (16,768,1024)
    const float* msk = (const float*)d_in[2];  // (16,1024,1024)
    const float* U   = (const float*)d_in[3];  // (768,768)
    float* out = (float*)d_out;

    char* ws = (char*)d_ws;
    unsigned char* At = (unsigned char*)ws;                   // 12,582,912
    unsigned char* Bt = (unsigned char*)(ws + 12582912);      // 12,582,912
    unsigned char* Ct = (unsigned char*)(ws + 25165824);      // 12,582,912
    unsigned char* Ut = (unsigned char*)(ws + 37748736);      //    589,824
    unsigned* keyA   = (unsigned*)(ws + 38338560);
    unsigned* keyB   = (unsigned*)(ws + 38404096);
    float*    scoreA = (float*)   (ws + 38469632);
    float*    scoreB = (float*)   (ws + 38535168);

    t_cast_U<<<dim3(DIM / 64, DIM / 64, 1), 256, 0, stream>>>(U, Ut, keyA, keyB);
    t_cast_AB<<<dim3(SEQA / 64, DIM / 64, 2 * BSZ), 256, 0, stream>>>(A, B, At, Bt);
    // x = s (8): consecutive blocks share the Ut e-slab; At slab reused at stride 8 (same XCD)
    k1_ua<<<dim3(SEQA / 128, DIM / 128, BSZ), 256, 0, stream>>>(At, Ut, Ct);
    // x = t (8): consecutive blocks share the Ct s-slab; Bt slab reused at stride 8 (same XCD)
    k2_align<<<dim3(SEQB / 128, SEQA / 128, BSZ), 256, 0, stream>>>(Ct, Bt, msk, keyA, keyB);
    k3_softmax<<<dim3(BSZ, 2), 256, 0, stream>>>(keyA, keyB, scoreA, scoreB);
    k4_out<<<dim3(BSZ * DIM / 4, 2), 256, 0, stream>>>(A, B, scoreA, scoreB, out);
}